// Round 23
// baseline (82.258 us; speedup 1.0000x reference)
//
#include <hip/hip_runtime.h>

// 10 steps of anisotropic 2D heat stencil, 48x48, B=16384.
// ROUND 23: INTRA-WAVE PHASE OVERLAP - 2 images per wave (grid 8192, TPB=64).
// Diagnosis: waves idle ~85% of lifetime; VALU time (~43us) + HBM time
// (~35us) ~= 78us wall -> load/compute/store phases serialize chip-wide.
// Fix: issue BOTH images' loads up front (18 dwordx4 in flight); image B's
// load latency hides under image A's ~5k-cycle compute; A's stores (operands
// consumed at issue) drain under B's compute. Prologue/coeffs shared.
// Registers: cc-precompute dropped (R13 "-2cv" form, +1 pk op/pair) to fit
// A(36)+B(36)+temp(36)+halos(33)+coeff(15) under waves_per_eu(2,3) ~170.
// Per image: lane 16x4, patch 3x12 as 6 v2f/row, rolled-x2 ping-pong Jacobi
// (u->m, m->u; m scratch inside body, zero copies), self-tied DPP ghosts
// (boundary lanes = dpp-invalid lanes keep frozen reflect ghost at no cost),
// per-row pipelined bpermute halos, WAR-safe restage after row 2.
// Ghosts = reflect pad of the INITIAL state (reference pads once).

typedef float v2f __attribute__((ext_vector_type(2)));

constexpr int NXY   = 48;
constexpr int CELLS = NXY * NXY;     // 2304
constexpr int NT    = 10;
constexpr int TPB   = 64;            // one wave per block

// lane i <- lane i-1 within each 16-lane DPP row; invalid (i%16==0) keeps oldv
__device__ __forceinline__ float dpp_up(float oldv, float src) {
    return __int_as_float(__builtin_amdgcn_update_dpp(
        __float_as_int(oldv), __float_as_int(src), 0x111, 0xF, 0xF, false));
}
// lane i <- lane i+1; invalid (i%16==15) keeps oldv
__device__ __forceinline__ float dpp_dn(float oldv, float src) {
    return __int_as_float(__builtin_amdgcn_update_dpp(
        __float_as_int(oldv), __float_as_int(src), 0x101, 0xF, 0xF, false));
}

__global__ __launch_bounds__(TPB)
__attribute__((amdgpu_waves_per_eu(2, 3)))
void pde_heat_kernel(
    const float* __restrict__ u0,
    const float* __restrict__ aw,
    const float* __restrict__ bw,
    float* __restrict__ out)
{
    const int lane = threadIdx.x;
    const int r = lane & 15;         // patch-row strip (16 strips of 3 rows)
    const int c = lane >> 4;         // patch-col strip (4 strips of 12 cols)
    const long long img0 = (long long)blockIdx.x * 2;
    const float4* __restrict__ u4a = (const float4*)(u0 + img0 * CELLS);
    const float4* __restrict__ u4b = u4a + (CELLS / 4);
    float4*       __restrict__ o4a = (float4*)(out + img0 * CELLS);
    float4*       __restrict__ o4b = o4a + (CELLS / 4);

    const int fb = r * 36 + c * 3;   // float4 index of patch (row0, col0)

    // ---- issue BOTH images' loads up front (18 x global_load_dwordx4) ----
    v2f A[3][6], B[3][6];
    #pragma unroll
    for (int ii = 0; ii < 3; ++ii)
        #pragma unroll
        for (int k = 0; k < 3; ++k) {
            float4 t = u4a[fb + 12 * ii + k];
            A[ii][2*k]   = (v2f){t.x, t.y};
            A[ii][2*k+1] = (v2f){t.z, t.w};
        }
    #pragma unroll
    for (int ii = 0; ii < 3; ++ii)
        #pragma unroll
        for (int k = 0; k < 3; ++k) {
            float4 t = u4b[fb + 12 * ii + k];
            B[ii][2*k]   = (v2f){t.x, t.y};
            B[ii][2*k+1] = (v2f){t.z, t.w};
        }

    // ---- coefficients: image-independent, computed ONCE for both images ----
    // (v_sin/v_cos take REVOLUTIONS: sin(2pi*x) = v_sin(x))
    // alpha(i) scales axis-0 diff: 0.5*dt/dx^2 = 1.152 ; beta(j): dt/dy^2 = 2.304
    const float a0 = aw[0], a1 = aw[1], a2 = aw[2];
    const float b0 = bw[0], b1 = bw[1], b2 = bw[2];
    float ca[3];
    #pragma unroll
    for (int ii = 0; ii < 3; ++ii) {
        float y = (float)(3 * r + ii) * (1.0f / 47.0f);
        ca[ii] = 1.152f * (a0 + a1 * __builtin_amdgcn_sinf(y)
                              + a2 * __builtin_amdgcn_sinf(2.0f * y));
    }
    v2f cb2[6];
    #pragma unroll
    for (int k = 0; k < 6; ++k) {
        float x0 = (float)(12 * c + 2 * k)     * (1.0f / 47.0f);
        float x1 = (float)(12 * c + 2 * k + 1) * (1.0f / 47.0f);
        cb2[k].x = 2.304f * (b0 + b1 * __builtin_amdgcn_cosf(x0)
                                + b2 * __builtin_amdgcn_cosf(2.0f * x0));
        cb2[k].y = 2.304f * (b0 + b1 * __builtin_amdgcn_cosf(x1)
                                + b2 * __builtin_amdgcn_cosf(2.0f * x1));
    }

    // ---- per-image halo state (re-primed per image) ----
    v2f ab[6], hb[6];                // persistent tied-DPP vertical halos
    float gH[3], hlp[3], hrp[3];     // frozen col ghosts + pipelined shuffles

    const int laneL = lane - 16, laneR = lane + 16;
    const bool cLft = (c == 0), cRgt = (c == 3);

    // init all halo state from an image's INITIAL buffer. Frozen ghosts:
    // top (r==0) = row 1 = own u[1]; bottom (r==15) = row 46 = own u[1];
    // boundary lanes are exactly the dpp-invalid lanes -> stay frozen.
    auto prime = [&](const v2f (&u)[3][6]) {
        #pragma unroll
        for (int k = 0; k < 6; ++k) { ab[k] = u[1][k]; hb[k] = u[1][k]; }
        #pragma unroll
        for (int k = 0; k < 6; ++k) {
            ab[k].x = dpp_up(ab[k].x, u[2][k].x);
            ab[k].y = dpp_up(ab[k].y, u[2][k].y);
            hb[k].x = dpp_dn(hb[k].x, u[0][k].x);
            hb[k].y = dpp_dn(hb[k].y, u[0][k].y);
        }
        #pragma unroll
        for (int ii = 0; ii < 3; ++ii)
            gH[ii] = cLft ? u[ii][0].y : u[ii][5].x;
        #pragma unroll
        for (int ii = 0; ii < 3; ++ii) {
            hlp[ii] = __shfl(u[ii][5].y, laneL);   // left nb's col 11
            hrp[ii] = __shfl(u[ii][0].x, laneR);   // right nb's col 0
        }
    };

    // one cell-pair: u' = cv + ca*(up+dn-2cv) + cb*(l+r-2cv)  (R13 form)
    auto cellpair = [&](int ii, int k, const v2f (&rowU)[6], const v2f (&rowM)[6],
                        const v2f (&rowD)[6], float lf, float rt) -> v2f {
        v2f cv = rowM[k];
        v2f s1 = rowU[k] + rowD[k];
        v2f s2;
        s2.x = lf + cv.y;
        s2.y = cv.x + rt;
        v2f uxx = s1 - 2.0f * cv;
        v2f uyy = s2 - 2.0f * cv;
        return cv + ca[ii] * uxx + cb2[k] * uyy;
    };

    // one Jacobi step src->dst; interior pairs first; halos restaged after
    // all same-step consumers (WAR-safe, R18 ordering)
    auto step = [&](const v2f (&src)[3][6], v2f (&dst)[3][6]) {
        float hl[3], hr[3];
        #pragma unroll
        for (int ii = 0; ii < 3; ++ii) {
            hl[ii] = cLft ? gH[ii] : hlp[ii];
            hr[ii] = cRgt ? gH[ii] : hrp[ii];
        }
        #pragma unroll
        for (int ii = 0; ii < 3; ++ii) {
            const v2f (&rowU)[6] = (ii == 0) ? ab : src[ii - 1];
            const v2f (&rowD)[6] = (ii == 2) ? hb : src[ii + 1];
            #pragma unroll
            for (int k = 1; k < 5; ++k)
                dst[ii][k] = cellpair(ii, k, rowU, src[ii], rowD,
                                      src[ii][k-1].y, src[ii][k+1].x);
            dst[ii][0] = cellpair(ii, 0, rowU, src[ii], rowD,
                                  hl[ii], src[ii][1].x);
            dst[ii][5] = cellpair(ii, 5, rowU, src[ii], rowD,
                                  src[ii][4].y, hr[ii]);
            // this row's next-step shuffles (hl/hr already latched)
            hlp[ii] = __shfl(dst[ii][5].y, laneL);
            hrp[ii] = __shfl(dst[ii][0].x, laneR);
            if (ii == 2) {
                #pragma unroll
                for (int k = 0; k < 6; ++k) {
                    ab[k].x = dpp_up(ab[k].x, dst[2][k].x);
                    ab[k].y = dpp_up(ab[k].y, dst[2][k].y);
                    hb[k].x = dpp_dn(hb[k].x, dst[0][k].x);
                    hb[k].y = dpp_dn(hb[k].y, dst[0][k].y);
                }
            }
        }
    };

    // run one image: 10 steps via rolled-x2 ping-pong (m scratch inside body)
    auto run10 = [&](v2f (&u)[3][6]) {
        #pragma unroll 1
        for (int it = 0; it < NT / 2; ++it) {
            v2f m[3][6];
            step(u, m);
            step(m, u);
        }
    };
    auto storeimg = [&](const v2f (&u)[3][6], float4* __restrict__ o4) {
        #pragma unroll
        for (int ii = 0; ii < 3; ++ii)
            #pragma unroll
            for (int k = 0; k < 3; ++k) {
                float4 t;
                t.x = u[ii][2*k].x;   t.y = u[ii][2*k].y;
                t.z = u[ii][2*k+1].x; t.w = u[ii][2*k+1].y;
                o4[fb + 12 * ii + k] = t;
            }
    };

    // ---- image A: compute (hides B's load latency), store (drains under B) ----
    prime(A);
    run10(A);
    storeimg(A, o4a);
    // ---- image B ----
    prime(B);
    run10(B);
    storeimg(B, o4b);
}

extern "C" void kernel_launch(void* const* d_in, const int* in_sizes, int n_in,
                              void* d_out, int out_size, void* d_ws, size_t ws_size,
                              hipStream_t stream) {
    const float* u0 = (const float*)d_in[0];
    const float* aw = (const float*)d_in[1];
    const float* bw = (const float*)d_in[2];
    float* out = (float*)d_out;

    const int B = in_sizes[0] / CELLS;   // 16384
    pde_heat_kernel<<<B / 2, TPB, 0, stream>>>(u0, aw, bw, out);
}